// Round 10
// baseline (251.533 us; speedup 1.0000x reference)
//
#include <hip/hip_runtime.h>
#include <math.h>

#define Bn 16
#define Nn 1024
#define Dn 128

typedef unsigned short ushort;
typedef unsigned long long u64;
typedef short short8 __attribute__((ext_vector_type(8)));
typedef float f32x4 __attribute__((ext_vector_type(4)));
typedef ushort us8 __attribute__((ext_vector_type(8)));
typedef ushort us4 __attribute__((ext_vector_type(4)));

__device__ __forceinline__ ushort f2bf(float f) {
    unsigned u = __float_as_uint(f);
    u += 0x7fff + ((u >> 16) & 1);           // RTN-even
    return (ushort)(u >> 16);
}
__device__ __forceinline__ float bf2f(ushort s) {
    return __uint_as_float(((unsigned)s) << 16);
}

// Fragment layouts (us8 units of 8 ushorts), tile = 16 rows:
//   h16f/hA16f: unit = rt_global*256 + kc*64 + m*4 + q    (rt 0..16383/16, kc 0..3)
//   Ef:         unit = ((b*64 + rt)*32 + kc)*64 + m*4 + q  (kc 0..31)
//   Tf:         unit = ((b*8  + nt)*32 + kc)*64 + m*4 + q  (B[nt*16+m][kc*32+q*8+e])
// bm (ballot layout): bm[(row_global*4 + chunk)*4 + j], chunk = col>>8, j = col&3,
//   bit index = (col>>2)&63.

// ---------------- K0: split weights (Ww->hi/lo, A^T->hi/lo) + Z init ----------------
__global__ __launch_bounds__(256) void k_wprep(const float* __restrict__ Ww,
                                               const float* __restrict__ A,
                                               ushort* __restrict__ Whi,
                                               ushort* __restrict__ Wlo,
                                               ushort* __restrict__ AThi,
                                               ushort* __restrict__ ATlo,
                                               float* __restrict__ Z) {
    int i = blockIdx.x * 256 + threadIdx.x;   // 0..16383
    float w = Ww[i];
    ushort wh = f2bf(w);
    Whi[i] = wh;
    Wlo[i] = f2bf(w - bf2f(wh));
    int e = i >> 7, d = i & 127;
    float a = A[d * Dn + e];
    ushort ah = f2bf(a);
    AThi[i] = ah;
    ATlo[i] = f2bf(a - bf2f(ah));
    Z[i] = (float)Nn;                         // non-edge exp(0) mass, m=0 shift
}

// ---------------- K0b: ballot bit-pack: wave reads 1KB coalesced, 4 ballots ----------------
__global__ __launch_bounds__(256) void k_pack(const float* __restrict__ adj,
                                              u64* __restrict__ bm) {
    int gwv = (blockIdx.x * 256 + threadIdx.x) >> 6;   // global wave 0..4095
    int lane = threadIdx.x & 63;
    #pragma unroll 4
    for (int it = 0; it < 16; ++it) {
        int pair = gwv * 16 + it;                      // (row,chunk), 65536 total
        const float* p = adj + (size_t)pair * 256 + lane * 4;
        float4 v = *(const float4*)p;
        u64 b0 = __ballot(v.x > 0.f);
        u64 b1 = __ballot(v.y > 0.f);
        u64 b2 = __ballot(v.z > 0.f);
        u64 b3 = __ballot(v.w > 0.f);
        if (lane == 0) {
            u64* d = bm + (size_t)pair * 4;
            d[0] = b0; d[1] = b1; d[2] = b2; d[3] = b3;
        }
    }
}

// ---------------- K1: fused MFMA h/hA; outputs h (f32) + h16f/hA16f (fragment layout) ----
__global__ __launch_bounds__(256) void k_h(const float* __restrict__ x,
                                           const float* __restrict__ Wb,
                                           const ushort* __restrict__ Whi,
                                           const ushort* __restrict__ Wlo,
                                           const ushort* __restrict__ AThi,
                                           const ushort* __restrict__ ATlo,
                                           float* __restrict__ h,
                                           ushort* __restrict__ h16f,
                                           ushort* __restrict__ hA16f) {
    int I0 = blockIdx.x * 16;
    int t = threadIdx.x, w = t >> 6, lane = t & 63;
    int m = lane & 15, q = lane >> 4;

    __shared__ float hs[16][Dn + 4];
    __shared__ float has[16][Dn + 4];

    const float* px = x + (size_t)(I0 + m) * Dn;
    f32x4 acc0 = {0,0,0,0}, acc1 = {0,0,0,0};
    #pragma unroll
    for (int ks = 0; ks < 4; ++ks) {
        int k0 = q * 8 + ks * 32;
        float v[8]; short8 ahi, alo;
        *(float4*)(v)     = *(const float4*)(px + k0);
        *(float4*)(v + 4) = *(const float4*)(px + k0 + 4);
        #pragma unroll
        for (int j = 0; j < 8; ++j) {
            ushort hi = f2bf(v[j]);
            ahi[j] = (short)hi;
            alo[j] = (short)f2bf(v[j] - bf2f(hi));
        }
        #pragma unroll
        for (int nn = 0; nn < 2; ++nn) {
            int brow = (w * 2 + nn) * 16 + m;
            short8 bhi = __builtin_bit_cast(short8, ((const us8*)(Whi + (size_t)brow * Dn))[q + ks * 4]);
            short8 blo = __builtin_bit_cast(short8, ((const us8*)(Wlo + (size_t)brow * Dn))[q + ks * 4]);
            f32x4 acc = nn ? acc1 : acc0;
            acc = __builtin_amdgcn_mfma_f32_16x16x32_bf16(ahi, bhi, acc, 0, 0, 0);
            acc = __builtin_amdgcn_mfma_f32_16x16x32_bf16(alo, bhi, acc, 0, 0, 0);
            acc = __builtin_amdgcn_mfma_f32_16x16x32_bf16(ahi, blo, acc, 0, 0, 0);
            if (nn) acc1 = acc; else acc0 = acc;
        }
    }
    #pragma unroll
    for (int nn = 0; nn < 2; ++nn) {
        int col = (w * 2 + nn) * 16 + m;
        float bias = Wb[col];
        f32x4 acc = nn ? acc1 : acc0;
        #pragma unroll
        for (int r = 0; r < 4; ++r) {
            int rl = q * 4 + r;
            float hv = acc[r] + bias;
            h[(size_t)(I0 + rl) * Dn + col] = hv;
            hs[rl][col] = hv;
        }
    }
    __syncthreads();

    f32x4 bcc0 = {0,0,0,0}, bcc1 = {0,0,0,0};
    #pragma unroll
    for (int ks = 0; ks < 4; ++ks) {
        int k0 = q * 8 + ks * 32;
        float v[8]; short8 ahi, alo;
        *(float4*)(v)     = *(const float4*)(&hs[m][k0]);
        *(float4*)(v + 4) = *(const float4*)(&hs[m][k0 + 4]);
        #pragma unroll
        for (int j = 0; j < 8; ++j) {
            ushort hi = f2bf(v[j]);
            ahi[j] = (short)hi;
            alo[j] = (short)f2bf(v[j] - bf2f(hi));
        }
        #pragma unroll
        for (int nn = 0; nn < 2; ++nn) {
            int brow = (w * 2 + nn) * 16 + m;
            short8 bhi = __builtin_bit_cast(short8, ((const us8*)(AThi + (size_t)brow * Dn))[q + ks * 4]);
            short8 blo = __builtin_bit_cast(short8, ((const us8*)(ATlo + (size_t)brow * Dn))[q + ks * 4]);
            f32x4 acc = nn ? bcc1 : bcc0;
            acc = __builtin_amdgcn_mfma_f32_16x16x32_bf16(ahi, bhi, acc, 0, 0, 0);
            acc = __builtin_amdgcn_mfma_f32_16x16x32_bf16(alo, bhi, acc, 0, 0, 0);
            acc = __builtin_amdgcn_mfma_f32_16x16x32_bf16(ahi, blo, acc, 0, 0, 0);
            if (nn) bcc1 = acc; else bcc0 = acc;
        }
    }
    #pragma unroll
    for (int nn = 0; nn < 2; ++nn) {
        int col = (w * 2 + nn) * 16 + m;
        f32x4 acc = nn ? bcc1 : bcc0;
        #pragma unroll
        for (int r = 0; r < 4; ++r)
            has[q * 4 + r][col] = acc[r];
    }
    __syncthreads();

    // fragment-layout conversion: thread t -> one us8 unit of h16f and hA16f
    {
        int kc = t >> 6, mm = (t >> 2) & 15, qq = t & 3;
        int cb = kc * 32 + qq * 8;
        us8 oh, oa;
        #pragma unroll
        for (int e = 0; e < 8; ++e) {
            oh[e] = f2bf(hs[mm][cb + e]);
            oa[e] = f2bf(has[mm][cb + e]);
        }
        size_t U = (size_t)(I0 >> 4) * 256 + kc * 64 + mm * 4 + qq;
        ((us8*)h16f)[U]  = oh;
        ((us8*)hA16f)[U] = oa;
    }
}

// ---------------- K3: scores: all-coalesced fragment loads (no staging, no pre-barrier),
//                  MFMA -> LDS -> ballot-mask/exp + colsum; E in fragment layout ---------
__global__ __launch_bounds__(256, 4) void k_scores(const ushort* __restrict__ h16f,
                                                   const ushort* __restrict__ hA16f,
                                                   const u64* __restrict__ bm,
                                                   ushort* __restrict__ Ef,
                                                   float* __restrict__ Z) {
    int L = blockIdx.x;
    int b    = ((L & 7) << 1) | (L >> 11);        // XCD-grouped batches
    int tile = (L >> 3) & 255;
    int I0 = (tile >> 4) << 6;
    int J0 = (tile & 15) << 6;
    int t = threadIdx.x, wid = t >> 6, lane = t & 63;
    int m = lane & 15, q = lane >> 4;

    __shared__ float sc[64][68];
    __shared__ float cz[4][64];

    const us8* Hf = (const us8*)h16f  + (size_t)b * 16384;
    const us8* Af = (const us8*)hA16f + (size_t)b * 16384;
    int off = m * 4 + q;
    int rtA = (I0 >> 4) + wid;

    f32x4 acc[4] = {};
    #pragma unroll
    for (int ks = 0; ks < 4; ++ks) {
        short8 a1 = __builtin_bit_cast(short8, Af[rtA * 256 + ks * 64 + off]);  // hA_I
        short8 a2 = __builtin_bit_cast(short8, Hf[rtA * 256 + ks * 64 + off]);  // h_I
        #pragma unroll
        for (int nt = 0; nt < 4; ++nt) {
            int rtB = (J0 >> 4) + nt;
            short8 b1 = __builtin_bit_cast(short8, Hf[rtB * 256 + ks * 64 + off]);
            short8 b2 = __builtin_bit_cast(short8, Af[rtB * 256 + ks * 64 + off]);
            acc[nt] = __builtin_amdgcn_mfma_f32_16x16x32_bf16(a1, b1, acc[nt], 0, 0, 0);
            acc[nt] = __builtin_amdgcn_mfma_f32_16x16x32_bf16(a2, b2, acc[nt], 0, 0, 0);
        }
    }

    #pragma unroll
    for (int nt = 0; nt < 4; ++nt)
        #pragma unroll
        for (int r = 0; r < 4; ++r)
            sc[wid * 16 + q * 4 + r][nt * 16 + m] = acc[nt][r];
    __syncthreads();

    int row16 = t >> 4, c = t & 15;
    int bitc = ((J0 >> 2) & 63) + c;
    float colsum[4] = {0.f, 0.f, 0.f, 0.f};
    #pragma unroll
    for (int it = 0; it < 4; ++it) {
        int row = it * 16 + row16;
        const u64* wp = bm + ((size_t)(b * Nn + I0 + row) * 4 + (J0 >> 8)) * 4;
        u64 w0 = wp[0], w1 = wp[1], w2 = wp[2], w3 = wp[3];
        float s4[4];
        *(float4*)s4 = *(const float4*)(&sc[row][c * 4]);
        us4 e4;
        u64 wj[4] = {w0, w1, w2, w3};
        #pragma unroll
        for (int j = 0; j < 4; ++j) {
            float ex = __expf(s4[j]);
            bool on = (wj[j] >> bitc) & 1;
            e4[j] = f2bf(on ? ex : 0.f);
            colsum[j] += on ? (ex - 1.0f) : 0.f;
        }
        size_t U = ((((size_t)b * 64 + (I0 >> 4) + it) * 32 + (J0 >> 5) + (c >> 3)) * 16 + row16) * 4
                 + ((c & 7) >> 1);
        *(us4*)(Ef + U * 8 + (c & 1) * 4) = e4;
    }
    #pragma unroll
    for (int j = 0; j < 4; ++j) {
        colsum[j] += __shfl_xor(colsum[j], 16, 64);
        colsum[j] += __shfl_xor(colsum[j], 32, 64);
    }
    if (lane < 16) {
        #pragma unroll
        for (int j = 0; j < 4; ++j) cz[wid][lane * 4 + j] = colsum[j];
    }
    __syncthreads();
    if (t < 64) {
        float s = cz[0][t] + cz[1][t] + cz[2][t] + cz[3][t];
        atomicAdd(&Z[b * Nn + J0 + t], s);
    }
}

// ---------------- K4: Tf = fragment-layout (src/Z)^T ----------------
__global__ __launch_bounds__(256) void k_prep(const float* __restrict__ src,
                                              const float* __restrict__ Z,
                                              ushort* __restrict__ Tf) {
    int b = blockIdx.y;
    int j0 = blockIdx.x * 64;
    int t = threadIdx.x;
    __shared__ float ls[64][129];
    __shared__ float iz[64];
    if (t < 64) iz[t] = 1.0f / Z[b * Nn + j0 + t];
    __syncthreads();
    #pragma unroll
    for (int it = 0; it < 32; ++it) {
        int idx = it * 256 + t;
        int j = idx >> 7, k = idx & 127;
        ls[j][k] = src[((size_t)b * Nn + j0 + j) * Dn + k] * iz[j];
    }
    __syncthreads();
    int k = t & 127, half = t >> 7;               // thread: d-row k, 32-j half
    us8 o[4];
    #pragma unroll
    for (int qq = 0; qq < 4; ++qq) {
        us8 tmp;
        #pragma unroll
        for (int e = 0; e < 8; ++e)
            tmp[e] = f2bf(ls[half * 32 + qq * 8 + e][k]);
        o[qq] = tmp;
    }
    size_t U = (((size_t)(k >> 4) * 32 + (j0 >> 5) + half) * 16 + (k & 15)) * 4;
    us8* dst = (us8*)(Tf + (size_t)b * 131072 + U * 8);
    dst[0] = o[0]; dst[1] = o[1]; dst[2] = o[2]; dst[3] = o[3];
}

// ---------------- K5: hop GEMM: fragment loads, 1024 blocks, waves split K (4x256),
//                  LDS partial reduce; fused relu+gate+lerp; Tf or out write ------------
__global__ __launch_bounds__(256, 4) void k_hop(const ushort* __restrict__ Ef,
                                                const ushort* __restrict__ Tf,
                                                const float* __restrict__ h,
                                                const float* __restrict__ Z,
                                                const float* __restrict__ gw,
                                                const float* __restrict__ gb,
                                                ushort* __restrict__ Tfn,
                                                float* __restrict__ out,
                                                int last) {
    int L = blockIdx.x;                           // 1024 blocks
    int b  = ((L & 7) << 1) | (L >> 9);           // XCD-grouped batches
    int rt = (L >> 3) & 63;
    int I0 = rt << 4;
    int t = threadIdx.x, w = t >> 6, lane = t & 63;
    int m = lane & 15, q = lane >> 4;

    __shared__ float red[4][16][132];             // 33.8 KB partials
    __shared__ ushort tt[128][16];                // 4 KB transpose buf

    const us8* pA = (const us8*)Ef + ((size_t)b * 64 + rt) * 2048;
    const us8* pB = (const us8*)Tf + (size_t)b * 16384;
    int off = m * 4 + q;

    f32x4 acc[8] = {};
    #pragma unroll 2
    for (int k8 = 0; k8 < 8; ++k8) {              // wave's K-quarter: kc = w*8+k8
        int kc = w * 8 + k8;
        short8 a = __builtin_bit_cast(short8, pA[kc * 64 + off]);
        #pragma unroll
        for (int nt = 0; nt < 8; ++nt)
            acc[nt] = __builtin_amdgcn_mfma_f32_16x16x32_bf16(
                a, __builtin_bit_cast(short8, pB[nt * 2048 + kc * 64 + off]), acc[nt], 0, 0, 0);
    }
    #pragma unroll
    for (int nt = 0; nt < 8; ++nt)
        #pragma unroll
        for (int r = 0; r < 4; ++r)
            red[w][q * 4 + r][nt * 16 + m] = acc[nt][r];
    __syncthreads();

    int row = t >> 4, c = t & 15;
    float gb0 = gb[0];
    float azv[8], hv[8];
    float gs = 0.f;
    size_t hbase = ((size_t)b * Nn + I0 + row) * Dn;
    #pragma unroll
    for (int j = 0; j < 8; ++j) {
        int k = c + 16 * j;
        float v = red[0][row][k] + red[1][row][k] + red[2][row][k] + red[3][row][k];
        v = fmaxf(v, 0.f);
        float hh = h[hbase + k];
        azv[j] = v; hv[j] = hh;
        gs += hh * gw[k] + v * gw[Dn + k];
    }
    gs += __shfl_xor(gs, 1, 64);
    gs += __shfl_xor(gs, 2, 64);
    gs += __shfl_xor(gs, 4, 64);
    gs += __shfl_xor(gs, 8, 64);                  // sum over the 16 c-lanes (row const)
    float coef = 1.0f / (1.0f + __expf(-(gs + gb0)));

    if (last) {
        #pragma unroll
        for (int j = 0; j < 8; ++j)
            out[hbase + c + 16 * j] = coef * hv[j] + (1.f - coef) * azv[j];
    } else {
        float iz = 1.0f / Z[b * Nn + I0 + row];
        #pragma unroll
        for (int j = 0; j < 8; ++j)
            tt[c + 16 * j][row] = f2bf((coef * hv[j] + (1.f - coef) * azv[j]) * iz);
        __syncthreads();
        int k = t >> 1, part = t & 1;             // Tf unit: nt=k>>4, kc=rt>>1, m=k&15, q=(rt&1)*2+part
        size_t U = ((size_t)b * 8 + (k >> 4)) * 2048 + (rt >> 1) * 64 + (k & 15) * 4
                 + ((rt & 1) << 1) + part;
        ((us8*)Tfn)[U] = *(const us8*)&tt[k][part * 8];
    }
}

extern "C" void kernel_launch(void* const* d_in, const int* in_sizes, int n_in,
                              void* d_out, int out_size, void* d_ws, size_t ws_size,
                              hipStream_t stream) {
    const float* x    = (const float*)d_in[0];   // [B,N,128]
    const float* adj  = (const float*)d_in[1];   // [B,N,N]
    const float* Ww   = (const float*)d_in[2];   // [128,128]
    const float* Wb   = (const float*)d_in[3];   // [128]
    const float* A    = (const float*)d_in[4];   // [128,128]
    const float* gw   = (const float*)d_in[5];   // [1,256]
    const float* gb   = (const float*)d_in[6];   // [1]
    float* out = (float*)d_out;                  // [B,N,128] f32

    char* ws = (char*)d_ws;
    float*  h     = (float*)(ws);                          // 8 MB f32
    ushort* h16f  = (ushort*)(ws + (8u << 20));            // 4 MB (dead after k_scores)
    ushort* hA16f = (ushort*)(ws + (12u << 20));           // 4 MB (dead after k_scores)
    ushort* Ta    = (ushort*)(ws + (8u << 20));            // aliases h16f  (Tf buffers)
    ushort* Tb    = (ushort*)(ws + (12u << 20));           // aliases hA16f
    ushort* E     = (ushort*)(ws + (16u << 20));           // 32 MB (fragment layout)
    float*  Z     = (float*)(ws + (48u << 20));            // 64 KB
    ushort* Whi   = (ushort*)(ws + (48u << 20) + (64u << 10));
    ushort* Wlo   = (ushort*)(ws + (48u << 20) + (96u << 10));
    ushort* AThi  = (ushort*)(ws + (48u << 20) + (128u << 10));
    ushort* ATlo  = (ushort*)(ws + (48u << 20) + (160u << 10));
    u64*    bm    = (u64*)(ws + (48u << 20) + (192u << 10));  // 2 MB bitmask
    // total ~50.2 MB

    k_wprep <<<64, 256, 0, stream>>>(Ww, A, Whi, Wlo, AThi, ATlo, Z);
    k_pack  <<<1024, 256, 0, stream>>>(adj, bm);
    k_h     <<<1024, 256, 0, stream>>>(x, Wb, Whi, Wlo, AThi, ATlo, h, h16f, hA16f);
    k_scores<<<4096, 256, 0, stream>>>(h16f, hA16f, bm, E, Z);
    k_prep  <<<dim3(16, Bn), 256, 0, stream>>>(h, Z, Ta);          // Tf0 = (h/Z)^T
    k_hop   <<<1024, 256, 0, stream>>>(E, Ta, h, Z, gw, gb, Tb, out, 0);
    k_hop   <<<1024, 256, 0, stream>>>(E, Tb, h, Z, gw, gb, Ta, out, 0);
    k_hop   <<<1024, 256, 0, stream>>>(E, Ta, h, Z, gw, gb, (ushort*)nullptr, out, 1);
}